// Round 3
// baseline (76.862 us; speedup 1.0000x reference)
//
#include <hip/hip_runtime.h>

typedef float f32x4 __attribute__((ext_vector_type(4)));
typedef __bf16 bf16x8 __attribute__((ext_vector_type(8)));
typedef unsigned short u16x8 __attribute__((ext_vector_type(8)));

#define NB 4
#define NH 16
#define TT 4096
#define DD 64
#define LOG2E 1.4426950408889634f
#define QSCALE (LOG2E * 0.125f)   // (1/sqrt(64)) * log2(e)
#define NEGB (-1.5e9f)            // large-negative in exp2 domain; exp2 -> 0

__device__ __forceinline__ unsigned short f2bf(float x) {
  unsigned u = __float_as_uint(x);
  u += 0x7fffu + ((u >> 16) & 1u);   // RNE
  return (unsigned short)(u >> 16);
}
__device__ __forceinline__ float bf2f(unsigned short h) {
  return __uint_as_float((unsigned)h << 16);
}
__device__ __forceinline__ unsigned cvt_pk_bf16(float a, float b) {
  unsigned r;
  asm("v_cvt_pk_bf16_f32 %0, %1, %2" : "=v"(r) : "v"(a), "v"(b));
  return r;
}
__device__ __forceinline__ float exp2_hw(float x) {
  float r;
  asm("v_exp_f32 %0, %1" : "=v"(r) : "v"(x));
  return r;
}

// LDS element-index swizzles (ushort units). K tiles are [128][64], V is [256][64].
// Read pattern is 16B at row-stride 128B -> XOR row bits into the 16B-slot index.
__device__ __forceinline__ int kswz(int key, int d) {
  return ((key << 6) + d) ^ ((key & 7) << 3);
}
// V is read as scalar u16 with 4 distinct keys (differing in bits 2..3) per instr.
__device__ __forceinline__ int vswz(int key, int d) {
  return ((key << 6) + d) ^ (((key >> 2) & 3) << 4);
}

__global__ __launch_bounds__(256, 2) void swa_fwd(
    const float* __restrict__ Qg, const float* __restrict__ Kg,
    const float* __restrict__ Vg, const float* __restrict__ Mg,
    float* __restrict__ Og) {
  // 64 KiB static LDS (no dynamic-shmem attribute needed): 2 blocks/CU.
  __shared__ unsigned short khs[128 * 64];   // 16 KiB  K hi
  __shared__ unsigned short kls[128 * 64];   // 16 KiB  K lo
  __shared__ unsigned short vvs[256 * 64];   // 32 KiB  V

  // XCD-bijective swizzle: 2048 blocks, 8 XCDs -> XCD x gets contiguous flat range.
  const int bid = blockIdx.x;
  const int flat = (bid & 7) * 256 + (bid >> 3);
  const int i = flat & 31;        // q-block
  const int bh = flat >> 5;       // b*NH + h
  const int b = bh >> 4;

  const int t = threadIdx.x;
  const int lane = t & 63;
  const int wid = t >> 6;
  const int lr = lane & 15;
  const int g = lane >> 4;

  const size_t base = (size_t)bh * (TT * DD);
  const float* Qb = Qg + base;
  const float* Kb = Kg + base;
  const float* Vb = Vg + base;
  const float* Mb = Mg + (size_t)b * TT;
  const int j0 = i * 128 - 128;           // window start (may be -128 for i==0)
  const int qrow0 = i * 128 + wid * 32;   // this wave's 32 rows

  // ---- early Q loads (in flight while staging K/V) ----
  f32x4 qraw[2][2][2];
#pragma unroll
  for (int nt = 0; nt < 2; ++nt)
#pragma unroll
    for (int s = 0; s < 2; ++s) {
      const float* qp = Qb + (size_t)(qrow0 + nt * 16 + lr) * DD + s * 32 + g * 8;
      qraw[nt][s][0] = *(const f32x4*)qp;
      qraw[nt][s][1] = *(const f32x4*)(qp + 4);
    }

  const int dg = (t & 7) * 8;   // 8 consecutive d per thread
  const int rowt = t >> 3;      // 32 rows per iter

  // ---- stage V (all 256 keys), bf16, swizzled ----
#pragma unroll
  for (int it = 0; it < 8; ++it) {
    int key = it * 32 + rowt;
    int j = j0 + key;
    j = j < 0 ? 0 : j;          // clamped like the reference (masked later)
    const float* src = Vb + (size_t)j * DD + dg;
    f32x4 a = *(const f32x4*)src;
    f32x4 c = *(const f32x4*)(src + 4);
    union { u16x8 v; unsigned short u[8]; } hv;
#pragma unroll
    for (int u = 0; u < 4; ++u) {
      hv.u[u] = f2bf(a[u]);
      hv.u[u + 4] = f2bf(c[u]);
    }
    *(u16x8*)(vvs + vswz(key, dg)) = hv.v;
  }

  // ---- K staging (hi/lo split), one 128-key half at a time ----
  auto stage_k = [&](int half) {
#pragma unroll
    for (int it = 0; it < 4; ++it) {
      int key = it * 32 + rowt;             // local 0..127
      int j = j0 + half * 128 + key;
      j = j < 0 ? 0 : j;
      const float* src = Kb + (size_t)j * DD + dg;
      f32x4 a = *(const f32x4*)src;
      f32x4 c = *(const f32x4*)(src + 4);
      union { u16x8 v; unsigned short u[8]; } hh, ll;
#pragma unroll
      for (int u = 0; u < 4; ++u) {
        unsigned short hx = f2bf(a[u]);
        hh.u[u] = hx;
        ll.u[u] = f2bf(a[u] - bf2f(hx));
        unsigned short hy = f2bf(c[u]);
        hh.u[u + 4] = hy;
        ll.u[u + 4] = f2bf(c[u] - bf2f(hy));
      }
      int e = kswz(key, dg);
      *(u16x8*)(khs + e) = hh.v;
      *(u16x8*)(kls + e) = ll.v;
    }
  };

  stage_k(0);
  __syncthreads();

  // ---- Q fragments: hi/lo split of q * (log2e/8) ----
  union bfr { u16x8 uv; unsigned short u[8]; bf16x8 v; };
  bf16x8 qh[2][2], ql[2][2];
#pragma unroll
  for (int nt = 0; nt < 2; ++nt)
#pragma unroll
    for (int s = 0; s < 2; ++s) {
      bfr H, L;
#pragma unroll
      for (int half = 0; half < 2; ++half)
#pragma unroll
        for (int u = 0; u < 4; ++u) {
          float x = qraw[nt][s][half][u] * QSCALE;
          unsigned short hx = f2bf(x);
          H.u[half * 4 + u] = hx;
          L.u[half * 4 + u] = f2bf(x - bf2f(hx));
        }
      qh[nt][s] = H.v;
      ql[nt][s] = L.v;
    }

  // S^T accumulator: acc[mt][nt] = scores[key-tile mt][qrow-tile nt]
  f32x4 acc[16][2];
#pragma unroll
  for (int mt = 0; mt < 16; ++mt)
#pragma unroll
    for (int nt = 0; nt < 2; ++nt)
      acc[mt][nt] = (f32x4){0.f, 0.f, 0.f, 0.f};

  // S^T = K * Q^T (swapped): A = K fragment, B = Q fragment.
  // 3 passes: Kh*Qh + Kl*Qh + Kh*Ql  (Kl*Ql ~ eps^2, dropped)
  auto qk_half = [&](int half) {
#pragma unroll
    for (int mt = 0; mt < 8; ++mt)
#pragma unroll
      for (int s = 0; s < 2; ++s) {
        int e = kswz(mt * 16 + lr, s * 32 + g * 8);
        bf16x8 kfh = *(const bf16x8*)(khs + e);
        bf16x8 kfl = *(const bf16x8*)(kls + e);
#pragma unroll
        for (int nt = 0; nt < 2; ++nt) {
          f32x4& a = acc[half * 8 + mt][nt];
          a = __builtin_amdgcn_mfma_f32_16x16x32_bf16(kfh, qh[nt][s], a, 0, 0, 0);
          a = __builtin_amdgcn_mfma_f32_16x16x32_bf16(kfl, qh[nt][s], a, 0, 0, 0);
          a = __builtin_amdgcn_mfma_f32_16x16x32_bf16(kfh, ql[nt][s], a, 0, 0, 0);
        }
      }
  };

  qk_half(0);
  __syncthreads();
  stage_k(1);
  __syncthreads();
  qk_half(1);

  // ---- softmax (log2 domain). lane's C value (mt,nt,r):
  //   key = mt*16 + 4*g + r ; qrow = nt*16 + lr
  float m0 = -3.0e38f, m1 = -3.0e38f;
#pragma unroll
  for (int mt = 0; mt < 16; ++mt) {
    int key4 = mt * 16 + 4 * g;
    int j = j0 + key4;                 // 4-aligned; never straddles validity edge
    f32x4 bv;
    if (j >= 0) {
      f32x4 mv = *(const f32x4*)(Mb + j);
      bv = mv * LOG2E;
    } else {
      bv = (f32x4){NEGB, NEGB, NEGB, NEGB};
    }
#pragma unroll
    for (int r = 0; r < 4; ++r) {
      acc[mt][0][r] += bv[r];
      acc[mt][1][r] += bv[r];
      m0 = fmaxf(m0, acc[mt][0][r]);
      m1 = fmaxf(m1, acc[mt][1][r]);
    }
  }
  m0 = fmaxf(m0, __shfl_xor(m0, 16));
  m0 = fmaxf(m0, __shfl_xor(m0, 32));
  m1 = fmaxf(m1, __shfl_xor(m1, 16));
  m1 = fmaxf(m1, __shfl_xor(m1, 32));

  float s0 = 0.f, s1 = 0.f;
#pragma unroll
  for (int mt = 0; mt < 16; ++mt)
#pragma unroll
    for (int r = 0; r < 4; ++r) {
      float p0 = exp2_hw(acc[mt][0][r] - m0);
      float p1 = exp2_hw(acc[mt][1][r] - m1);
      acc[mt][0][r] = p0;
      acc[mt][1][r] = p1;
      s0 += p0;
      s1 += p1;
    }
  s0 += __shfl_xor(s0, 16);
  s0 += __shfl_xor(s0, 32);
  s1 += __shfl_xor(s1, 16);
  s1 += __shfl_xor(s1, 32);
  const float inv0 = 1.f / s0;
  const float inv1 = 1.f / s1;

  // ---- PV: out = P * V.  A = P (in regs, natural layout), B = V from LDS,
  // with IDENTICAL per-slot key permutation sigma(g,j) = 32c + 16*(j>>2) + 4g + (j&3)
  f32x4 oacc[2][4];
#pragma unroll
  for (int nt = 0; nt < 2; ++nt)
#pragma unroll
    for (int dt = 0; dt < 4; ++dt)
      oacc[nt][dt] = (f32x4){0.f, 0.f, 0.f, 0.f};

#pragma unroll
  for (int c = 0; c < 8; ++c) {
    union { unsigned w[4]; bf16x8 v; } pa[2];
#pragma unroll
    for (int nt = 0; nt < 2; ++nt) {
      pa[nt].w[0] = cvt_pk_bf16(acc[2 * c][nt][0], acc[2 * c][nt][1]);
      pa[nt].w[1] = cvt_pk_bf16(acc[2 * c][nt][2], acc[2 * c][nt][3]);
      pa[nt].w[2] = cvt_pk_bf16(acc[2 * c + 1][nt][0], acc[2 * c + 1][nt][1]);
      pa[nt].w[3] = cvt_pk_bf16(acc[2 * c + 1][nt][2], acc[2 * c + 1][nt][3]);
    }
#pragma unroll
    for (int dt = 0; dt < 4; ++dt) {
      union { unsigned short u[8]; bf16x8 v; } vb;
      int d = dt * 16 + lr;
#pragma unroll
      for (int jj = 0; jj < 8; ++jj) {
        int key = 32 * c + 16 * (jj >> 2) + 4 * g + (jj & 3);
        vb.u[jj] = vvs[vswz(key, d)];
      }
#pragma unroll
      for (int nt = 0; nt < 2; ++nt)
        oacc[nt][dt] = __builtin_amdgcn_mfma_f32_16x16x32_bf16(pa[nt].v, vb.v,
                                                               oacc[nt][dt], 0, 0, 0);
    }
  }

  // ---- epilogue: out C layout -> row = nt*16 + 4g + r, col = dt*16 + lr
  float* Ob = Og + base + (size_t)qrow0 * DD;
#pragma unroll
  for (int nt = 0; nt < 2; ++nt) {
#pragma unroll
    for (int r = 0; r < 4; ++r) {
      float iv = __shfl(nt ? inv1 : inv0, 4 * g + r);
      int row = nt * 16 + 4 * g + r;
#pragma unroll
      for (int dt = 0; dt < 4; ++dt)
        Ob[(size_t)row * DD + dt * 16 + lr] = oacc[nt][dt][r] * iv;
    }
  }
}

extern "C" void kernel_launch(void* const* d_in, const int* in_sizes, int n_in,
                              void* d_out, int out_size, void* d_ws, size_t ws_size,
                              hipStream_t stream) {
  (void)in_sizes; (void)n_in; (void)out_size; (void)d_ws; (void)ws_size;
  const float* Q = (const float*)d_in[0];
  const float* K = (const float*)d_in[1];
  const float* V = (const float*)d_in[2];
  const float* M = (const float*)d_in[3];
  float* O = (float*)d_out;

  hipLaunchKernelGGL(swa_fwd, dim3(NB * NH * 32), dim3(256), 0, stream,
                     Q, K, V, M, O);
}